// Round 1
// baseline (3281.591 us; speedup 1.0000x reference)
//
#include <hip/hip_runtime.h>
#include <stdint.h>

typedef __bf16 bf16;
typedef __bf16 bf16x8 __attribute__((ext_vector_type(8)));
typedef __bf16 bf16x4 __attribute__((ext_vector_type(4)));
typedef float f32x4 __attribute__((ext_vector_type(4)));

#define DEVINL __device__ __forceinline__

constexpr int B_ = 2, S_ = 2048, D_ = 4096, H_ = 32, DH_ = 128, I_ = 11008;
constexpr int T_ = B_ * S_; // 4096 tokens

// async global->LDS, 16B per lane. LDS dest is wave-uniform base + lane*16,
// so callers MUST pass lane-linear lds addresses (j = i*256 + tid pattern).
DEVINL void async16(void* lds, const void* g) {
  __builtin_amdgcn_global_load_lds(
      (const __attribute__((address_space(1))) void*)g,
      (__attribute__((address_space(3))) void*)lds, 16, 0, 0);
}

DEVINL f32x4 mfma16(bf16x8 a, bf16x8 b, f32x4 c) {
  return __builtin_amdgcn_mfma_f32_16x16x32_bf16(a, b, c, 0, 0, 0);
}

// ---------------------------------------------------------------------------
// fp32 [K,N] -> bf16 [N,K] cast + transpose, 64x64 tiles via LDS
// ---------------------------------------------------------------------------
__global__ __launch_bounds__(256)
void cast_transpose(const float* __restrict__ in, bf16* __restrict__ out,
                    const int K, const int N)
{
  __shared__ float t[64][65];
  const int tx = threadIdx.x & 15, ty = threadIdx.x >> 4;
  const int n0 = blockIdx.x * 64, k0 = blockIdx.y * 64;
#pragma unroll
  for (int j = 0; j < 4; ++j) {
    const int r = ty + j * 16;
    const float4 vv = *(const float4*)&in[(size_t)(k0 + r) * N + n0 + tx * 4];
    t[r][tx * 4 + 0] = vv.x;
    t[r][tx * 4 + 1] = vv.y;
    t[r][tx * 4 + 2] = vv.z;
    t[r][tx * 4 + 3] = vv.w;
  }
  __syncthreads();
#pragma unroll
  for (int j = 0; j < 4; ++j) {
    const int n = ty + j * 16;
    bf16x4 o;
    o[0] = (bf16)t[tx * 4 + 0][n];
    o[1] = (bf16)t[tx * 4 + 1][n];
    o[2] = (bf16)t[tx * 4 + 2][n];
    o[3] = (bf16)t[tx * 4 + 3][n];
    *(bf16x4*)&out[(size_t)(n0 + n) * K + k0 + tx * 4] = o;
  }
}

// ---------------------------------------------------------------------------
// RMSNorm: fp32 [rows, 4096] -> bf16, one block per row
// ---------------------------------------------------------------------------
__global__ __launch_bounds__(256)
void rmsnorm_k(const float* __restrict__ x, const float* __restrict__ w,
               bf16* __restrict__ out)
{
  const int row = blockIdx.x;
  const int tid = threadIdx.x;
  const float* xr = x + (size_t)row * D_;
  float4 v[4];
  float ss = 0.f;
#pragma unroll
  for (int i = 0; i < 4; ++i) {
    v[i] = *(const float4*)&xr[tid * 4 + i * 1024];
    ss += v[i].x * v[i].x + v[i].y * v[i].y + v[i].z * v[i].z + v[i].w * v[i].w;
  }
#pragma unroll
  for (int off = 32; off > 0; off >>= 1) ss += __shfl_xor(ss, off);
  __shared__ float red[4];
  if ((tid & 63) == 0) red[tid >> 6] = ss;
  __syncthreads();
  const float tot = red[0] + red[1] + red[2] + red[3];
  const float sc = rsqrtf(tot * (1.f / D_) + 1e-6f);
#pragma unroll
  for (int i = 0; i < 4; ++i) {
    const float4 wv = *(const float4*)&w[tid * 4 + i * 1024];
    bf16x4 o;
    o[0] = (bf16)(v[i].x * sc * wv.x);
    o[1] = (bf16)(v[i].y * sc * wv.y);
    o[2] = (bf16)(v[i].z * sc * wv.z);
    o[3] = (bf16)(v[i].w * sc * wv.w);
    *(bf16x4*)&out[(size_t)row * D_ + tid * 4 + i * 1024] = o;
  }
}

// ---------------------------------------------------------------------------
// GEMM: C[M,N] = A[M,K](bf16) x BT[N,K](bf16), 128x128 tile, BK=64,
// mfma_f32_16x16x32_bf16, global_load_lds 16B staging, XOR-swizzled LDS.
// MODE 0: +bias, scatter to q/k/v [B,H,S,Dh] (outp = q base, k/v contiguous)
// MODE 1: out fp32 = res + acc   (o-proj + residual)
// MODE 2: out bf16 = acc         (gate-up, plain)
// MODE 3: out fp32 = res + acc   (down-proj + residual -> d_out)
// ---------------------------------------------------------------------------
template<int MODE>
__global__ __launch_bounds__(256)
void gemm_bt(const bf16* __restrict__ A, const bf16* __restrict__ BT,
             const int M, const int N, const int K,
             const float* __restrict__ res, const float* __restrict__ bias,
             void* __restrict__ outp)
{
  __shared__ bf16 Al[128 * 64];
  __shared__ bf16 Bl[128 * 64];
  const int tid = threadIdx.x;
  const int lane = tid & 63, wave = tid >> 6;
  const int wm = wave & 1, wn = wave >> 1;
  const int quad = lane >> 4, l16 = lane & 15;
  const int m0 = blockIdx.y * 128, n0 = blockIdx.x * 128;

  const f32x4 fz = {0.f, 0.f, 0.f, 0.f};
  f32x4 acc[4][4];
#pragma unroll
  for (int a = 0; a < 4; ++a)
#pragma unroll
    for (int b = 0; b < 4; ++b) acc[a][b] = fz;

  const bf16* Abase = A + (size_t)m0 * K;
  const bf16* Bbase = BT + (size_t)n0 * K;

  for (int k0 = 0; k0 < K; k0 += 64) {
#pragma unroll
    for (int i = 0; i < 4; ++i) {
      const int j = i * 256 + tid;
      const int r = j >> 3;
      const int c = (j & 7) ^ (r & 7);   // XOR swizzle (8 chunks of 8 bf16)
      async16(&Al[j * 8], &Abase[(size_t)r * K + k0 + c * 8]);
      async16(&Bl[j * 8], &Bbase[(size_t)r * K + k0 + c * 8]);
    }
    __syncthreads();
#pragma unroll
    for (int ks = 0; ks < 2; ++ks) {
      bf16x8 af[4], bfv[4];
#pragma unroll
      for (int t = 0; t < 4; ++t) {
        const int m = wm * 64 + t * 16 + l16;
        af[t] = *(const bf16x8*)&Al[((m * 8) + ((ks * 4 + quad) ^ (m & 7))) * 8];
        const int n = wn * 64 + t * 16 + l16;
        bfv[t] = *(const bf16x8*)&Bl[((n * 8) + ((ks * 4 + quad) ^ (n & 7))) * 8];
      }
#pragma unroll
      for (int mt = 0; mt < 4; ++mt)
#pragma unroll
        for (int nt = 0; nt < 4; ++nt)
          acc[mt][nt] = mfma16(af[mt], bfv[nt], acc[mt][nt]);
    }
    __syncthreads();
  }

#pragma unroll
  for (int mt = 0; mt < 4; ++mt) {
#pragma unroll
    for (int nt = 0; nt < 4; ++nt) {
      const int col = n0 + wn * 64 + nt * 16 + l16;
#pragma unroll
      for (int r = 0; r < 4; ++r) {
        const int row = m0 + wm * 64 + mt * 16 + quad * 4 + r;
        float v = acc[mt][nt][r];
        if constexpr (MODE == 0) {
          v += bias[col];
          const int b = row >> 11, s = row & (S_ - 1);
          const int which = col >> 12, rr = col & (D_ - 1);
          const int h = rr >> 7, d = rr & (DH_ - 1);
          ((bf16*)outp)[(size_t)which * ((size_t)T_ * D_) +
                        ((size_t)(b * H_ + h) * S_ + s) * DH_ + d] = (bf16)v;
        } else if constexpr (MODE == 1) {
          const size_t idx = (size_t)row * N + col;
          ((float*)outp)[idx] = res[idx] + v;
        } else if constexpr (MODE == 2) {
          ((bf16*)outp)[(size_t)row * N + col] = (bf16)v;
        } else {
          const size_t idx = (size_t)row * N + col;
          ((float*)outp)[idx] = res[idx] + v;
        }
      }
    }
  }
}

// ---------------------------------------------------------------------------
// RoPE in-place on q,k [B,H,S,128]; pair (i, i+64), one thread per pair
// ---------------------------------------------------------------------------
__global__ __launch_bounds__(256)
void rope_qk(bf16* __restrict__ q, bf16* __restrict__ kk,
             const int* __restrict__ pos)
{
  const int idx = blockIdx.x * 256 + threadIdx.x; // B*H*S*64
  const int i = idx & 63;
  const int s = (idx >> 6) & (S_ - 1);
  const int bh = idx >> 17;
  const int b = bh >> 5;
  const int p = pos[b * S_ + s];
  const float fr = exp2f((float)i * (-13.287712379549449f / 64.f));
  const float ang = (float)p * fr;
  const float cs = cosf(ang), sn = sinf(ang);
  const size_t base = ((size_t)bh * S_ + s) * DH_ + i;
  {
    const float x1 = (float)q[base], x2 = (float)q[base + 64];
    q[base]      = (bf16)(x1 * cs - x2 * sn);
    q[base + 64] = (bf16)(x2 * cs + x1 * sn);
  }
  {
    const float x1 = (float)kk[base], x2 = (float)kk[base + 64];
    kk[base]      = (bf16)(x1 * cs - x2 * sn);
    kk[base + 64] = (bf16)(x2 * cs + x1 * sn);
  }
}

// ---------------------------------------------------------------------------
// V [bh, s, d] -> VT [bh, d, s], 64x64 tiles
// ---------------------------------------------------------------------------
__global__ __launch_bounds__(256)
void transpose_v(const bf16* __restrict__ in, bf16* __restrict__ out)
{
  __shared__ bf16 t[64][72];
  const int tx = threadIdx.x & 15, ty = threadIdx.x >> 4;
  const int bh = blockIdx.z;
  const int s0 = blockIdx.x * 64, d0 = blockIdx.y * 64;
#pragma unroll
  for (int j = 0; j < 4; ++j) {
    const int r = ty + j * 16;
    const bf16x4 vv = *(const bf16x4*)&in[((size_t)bh * S_ + s0 + r) * DH_ + d0 + tx * 4];
    t[r][tx * 4 + 0] = vv[0];
    t[r][tx * 4 + 1] = vv[1];
    t[r][tx * 4 + 2] = vv[2];
    t[r][tx * 4 + 3] = vv[3];
  }
  __syncthreads();
#pragma unroll
  for (int j = 0; j < 4; ++j) {
    const int d = ty + j * 16;
    bf16x4 o;
    o[0] = t[tx * 4 + 0][d];
    o[1] = t[tx * 4 + 1][d];
    o[2] = t[tx * 4 + 2][d];
    o[3] = t[tx * 4 + 3][d];
    *(bf16x4*)&out[((size_t)bh * DH_ + d0 + d) * S_ + s0 + tx * 4] = o;
  }
}

// ---------------------------------------------------------------------------
// Flash attention, causal. Block = one (bh, 128-row q-tile); 4 waves,
// wave w owns q rows [w*32, w*32+32). K-tiles of 64. P round-trips via LDS.
// ---------------------------------------------------------------------------
__global__ __launch_bounds__(256)
void flash_attn(const bf16* __restrict__ q, const bf16* __restrict__ kv,
                const bf16* __restrict__ vt, bf16* __restrict__ out)
{
  __shared__ bf16 Kl[64 * 128];  // [kk][d], 16-chunk XOR swizzle
  __shared__ bf16 Vl[128 * 64];  // [d][kk], 8-chunk XOR swizzle
  __shared__ bf16 Pl[128 * 64];  // [qr][kk], 8-chunk XOR swizzle (wave-private rows)
  const int tid = threadIdx.x, lane = tid & 63, wave = tid >> 6;
  const int quad = lane >> 4, l16 = lane & 15;
  const int qt = blockIdx.x, bh = blockIdx.y;
  const int qbase = qt * 128;
  const float scale = 0.08838834764831845f; // 128^-0.5

  bf16x8 qf[2][4];
#pragma unroll
  for (int mt = 0; mt < 2; ++mt) {
    const size_t rb = ((size_t)bh * S_ + qbase + wave * 32 + mt * 16 + l16) * DH_;
#pragma unroll
    for (int dk = 0; dk < 4; ++dk)
      qf[mt][dk] = *(const bf16x8*)&q[rb + dk * 32 + quad * 8];
  }

  const f32x4 fz = {0.f, 0.f, 0.f, 0.f};
  f32x4 o[2][8];
#pragma unroll
  for (int a = 0; a < 2; ++a)
#pragma unroll
    for (int b = 0; b < 8; ++b) o[a][b] = fz;
  float mi[2][4], li[2][4];
#pragma unroll
  for (int a = 0; a < 2; ++a)
#pragma unroll
    for (int r = 0; r < 4; ++r) { mi[a][r] = -1e30f; li[a][r] = 0.f; }

  const int nkt = 2 * qt + 2;
  for (int kt = 0; kt < nkt; ++kt) {
#pragma unroll
    for (int i = 0; i < 4; ++i) {
      const int j = i * 256 + tid;
      { const int r = j >> 4, c = (j & 15) ^ (r & 15);
        async16(&Kl[j * 8], &kv[((size_t)bh * S_ + kt * 64 + r) * DH_ + c * 8]); }
      { const int r = j >> 3, c = (j & 7) ^ (r & 7);
        async16(&Vl[j * 8], &vt[((size_t)bh * DH_ + r) * S_ + kt * 64 + c * 8]); }
    }
    __syncthreads();

    // S = Q K^T  (sc tiles: 2 m x 4 n of 16x16)
    f32x4 sc4[2][4];
#pragma unroll
    for (int a = 0; a < 2; ++a)
#pragma unroll
      for (int b = 0; b < 4; ++b) sc4[a][b] = fz;
#pragma unroll
    for (int dk = 0; dk < 4; ++dk) {
      bf16x8 kf[4];
#pragma unroll
      for (int nt = 0; nt < 4; ++nt) {
        const int kkr = nt * 16 + l16;
        kf[nt] = *(const bf16x8*)&Kl[((kkr * 16) + ((dk * 4 + quad) ^ (kkr & 15))) * 8];
      }
#pragma unroll
      for (int mt = 0; mt < 2; ++mt)
#pragma unroll
        for (int nt = 0; nt < 4; ++nt)
          sc4[mt][nt] = mfma16(qf[mt][dk], kf[nt], sc4[mt][nt]);
    }

    const bool domask = (kt >= 2 * qt);
    float mnew[2][4], al[2][4];
#pragma unroll
    for (int mt = 0; mt < 2; ++mt)
#pragma unroll
      for (int r = 0; r < 4; ++r) {
        float rm = -1e30f;
#pragma unroll
        for (int nt = 0; nt < 4; ++nt) {
          float vv = sc4[mt][nt][r] * scale;
          if (domask) {
            const int kg = kt * 64 + nt * 16 + l16;
            const int qg = qbase + wave * 32 + mt * 16 + quad * 4 + r;
            if (kg > qg) vv = -1e30f;
          }
          sc4[mt][nt][r] = vv;
          rm = fmaxf(rm, vv);
        }
#pragma unroll
        for (int off = 8; off > 0; off >>= 1) rm = fmaxf(rm, __shfl_xor(rm, off));
        const float mn = fmaxf(mi[mt][r], rm);
        mnew[mt][r] = mn;
        al[mt][r] = __expf(mi[mt][r] - mn);
        mi[mt][r] = mn;
      }
#pragma unroll
    for (int mt = 0; mt < 2; ++mt)
#pragma unroll
      for (int r = 0; r < 4; ++r) {
        float lsum = 0.f;
        const int qr = wave * 32 + mt * 16 + quad * 4 + r;
#pragma unroll
        for (int nt = 0; nt < 4; ++nt) {
          const float p = __expf(sc4[mt][nt][r] - mnew[mt][r]);
          lsum += p;
          const int kk = nt * 16 + l16;
          Pl[((qr * 8) + ((kk >> 3) ^ (qr & 7))) * 8 + (kk & 7)] = (bf16)p;
        }
#pragma unroll
        for (int off = 8; off > 0; off >>= 1) lsum += __shfl_xor(lsum, off);
        li[mt][r] = li[mt][r] * al[mt][r] + lsum;
      }
#pragma unroll
    for (int mt = 0; mt < 2; ++mt)
#pragma unroll
      for (int nt = 0; nt < 8; ++nt)
#pragma unroll
        for (int r = 0; r < 4; ++r) o[mt][nt][r] *= al[mt][r];

    // O += P V
#pragma unroll
    for (int dk2 = 0; dk2 < 2; ++dk2) {
      bf16x8 pf[2];
#pragma unroll
      for (int mt = 0; mt < 2; ++mt) {
        const int m = wave * 32 + mt * 16 + l16;
        pf[mt] = *(const bf16x8*)&Pl[((m * 8) + ((dk2 * 4 + quad) ^ (m & 7))) * 8];
      }
#pragma unroll
      for (int nt = 0; nt < 8; ++nt) {
        const int d = nt * 16 + l16;
        const bf16x8 vf = *(const bf16x8*)&Vl[((d * 8) + ((dk2 * 4 + quad) ^ (d & 7))) * 8];
#pragma unroll
        for (int mt = 0; mt < 2; ++mt)
          o[mt][nt] = mfma16(pf[mt], vf, o[mt][nt]);
      }
    }
    __syncthreads();
  }

  const int b = bh >> 5, h = bh & 31;
#pragma unroll
  for (int mt = 0; mt < 2; ++mt)
#pragma unroll
    for (int r = 0; r < 4; ++r) {
      const float inv = 1.f / li[mt][r];
      const int qg = qbase + wave * 32 + mt * 16 + quad * 4 + r;
#pragma unroll
      for (int nt = 0; nt < 8; ++nt) {
        const int d = nt * 16 + l16;
        out[((size_t)b * S_ + qg) * D_ + h * DH_ + d] = (bf16)(o[mt][nt][r] * inv);
      }
    }
}

// ---------------------------------------------------------------------------
// SwiGLU: act[m,n] = silu(gu[m,n]) * gu[m,n+I], 8 elems/thread
// ---------------------------------------------------------------------------
__global__ __launch_bounds__(256)
void silu_mul(const bf16* __restrict__ gu, bf16* __restrict__ act)
{
  const size_t idx = ((size_t)blockIdx.x * 256 + threadIdx.x) * 8;
  const size_t m = idx / I_;
  const size_t n = idx - m * I_;
  const bf16x8 g = *(const bf16x8*)&gu[m * (size_t)(2 * I_) + n];
  const bf16x8 u = *(const bf16x8*)&gu[m * (size_t)(2 * I_) + n + I_];
  bf16x8 r;
#pragma unroll
  for (int c = 0; c < 8; ++c) {
    const float gf = (float)g[c], uf = (float)u[c];
    r[c] = (bf16)(gf / (1.f + __expf(-gf)) * uf);
  }
  *(bf16x8*)&act[idx] = r;
}

// ---------------------------------------------------------------------------
extern "C" void kernel_launch(void* const* d_in, const int* in_sizes, int n_in,
                              void* d_out, int out_size, void* d_ws, size_t ws_size,
                              hipStream_t stream)
{
  const float* hidden  = (const float*)d_in[0];
  const int*   pos     = (const int*)d_in[1];
  const float* ln1_w   = (const float*)d_in[2];
  const float* w_qkv   = (const float*)d_in[3];
  const float* b_qkv   = (const float*)d_in[4];
  const float* w_o     = (const float*)d_in[5];
  const float* ln2_w   = (const float*)d_in[6];
  const float* w_gu    = (const float*)d_in[7];
  const float* w_down  = (const float*)d_in[8];

  char* ws = (char*)d_ws;
  const size_t off_wqkvT = 0;                                   // bf16 [12288,4096]
  const size_t off_woT   = off_wqkvT + (size_t)12288 * 4096 * 2;
  const size_t off_wguT  = off_woT   + (size_t)4096 * 4096 * 2; // bf16 [22016,4096]
  const size_t off_wdT   = off_wguT  + (size_t)22016 * 4096 * 2;// bf16 [4096,11008]
  const size_t off_xn    = off_wdT   + (size_t)4096 * 11008 * 2;// bf16 [4096,4096] (reused ln2)
  const size_t off_q     = off_xn    + (size_t)4096 * 4096 * 2; // bf16 [B,H,S,128]
  const size_t off_k     = off_q     + (size_t)16777216 * 2;
  const size_t off_v     = off_k     + (size_t)16777216 * 2;
  const size_t off_vt    = off_v     + (size_t)16777216 * 2;
  const size_t off_ao    = off_vt    + (size_t)16777216 * 2;    // bf16 [T,D]
  const size_t off_h2    = off_ao    + (size_t)16777216 * 2;    // fp32 [T,D]
  const size_t off_gu    = off_h2    + (size_t)4096 * 4096 * 4; // bf16 [T,22016]
  const size_t off_act   = off_q;   // q/k/v/vt dead by MLP time; bf16 [T,11008]

  bf16* wqkvT = (bf16*)(ws + off_wqkvT);
  bf16* woT   = (bf16*)(ws + off_woT);
  bf16* wguT  = (bf16*)(ws + off_wguT);
  bf16* wdT   = (bf16*)(ws + off_wdT);
  bf16* xn    = (bf16*)(ws + off_xn);
  bf16* qb    = (bf16*)(ws + off_q);
  bf16* kb    = (bf16*)(ws + off_k);
  bf16* vb    = (bf16*)(ws + off_v);
  bf16* vtb   = (bf16*)(ws + off_vt);
  bf16* aob   = (bf16*)(ws + off_ao);
  float* h2   = (float*)(ws + off_h2);
  bf16* gub   = (bf16*)(ws + off_gu);
  bf16* actb  = (bf16*)(ws + off_act);

  // 1) weights: fp32 [K,N] -> bf16 [N,K]
  cast_transpose<<<dim3(12288/64, 4096/64), 256, 0, stream>>>(w_qkv, wqkvT, 4096, 12288);
  cast_transpose<<<dim3(4096/64, 4096/64),  256, 0, stream>>>(w_o,   woT,   4096, 4096);
  cast_transpose<<<dim3(22016/64, 4096/64), 256, 0, stream>>>(w_gu,  wguT,  4096, 22016);
  cast_transpose<<<dim3(4096/64, 11008/64), 256, 0, stream>>>(w_down,wdT,  11008, 4096);

  // 2) ln1
  rmsnorm_k<<<T_, 256, 0, stream>>>(hidden, ln1_w, xn);

  // 3) qkv = xn @ w_qkv + b, scatter to q/k/v [B,H,S,128]
  gemm_bt<0><<<dim3(12288/128, T_/128), 256, 0, stream>>>(xn, wqkvT, T_, 12288, 4096,
                                                          nullptr, b_qkv, qb);
  // 4) rope on q,k
  rope_qk<<<(B_*H_*S_*64)/256, 256, 0, stream>>>(qb, kb, pos);

  // 5) v -> v^T
  transpose_v<<<dim3(S_/64, DH_/64, B_*H_), 256, 0, stream>>>(vb, vtb);

  // 6) attention
  flash_attn<<<dim3(S_/128, B_*H_), 256, 0, stream>>>(qb, kb, vtb, aob);

  // 7) h2 = hidden + attn_out @ w_o
  gemm_bt<1><<<dim3(4096/128, T_/128), 256, 0, stream>>>(aob, woT, T_, 4096, 4096,
                                                         hidden, nullptr, h2);
  // 8) ln2
  rmsnorm_k<<<T_, 256, 0, stream>>>(h2, ln2_w, xn);

  // 9) gu = xn @ w_gate_up
  gemm_bt<2><<<dim3(22016/128, T_/128), 256, 0, stream>>>(xn, wguT, T_, 22016, 4096,
                                                          nullptr, nullptr, gub);
  // 10) act = silu(g) * u
  silu_mul<<<(T_*(size_t)I_)/8/256, 256, 0, stream>>>(gub, actb);

  // 11) out = h2 + act @ w_down
  gemm_bt<3><<<dim3(4096/128, T_/128), 256, 0, stream>>>(actb, wdT, T_, 4096, 11008,
                                                         h2, nullptr, (float*)d_out);
}